// Round 1
// baseline (274.552 us; speedup 1.0000x reference)
//
#include <hip/hip_runtime.h>
#include <math.h>

#ifndef M_PI
#define M_PI 3.14159265358979323846
#endif

constexpr int KDIM = 128;
constexpr int LTOT = 8192;
constexpr int TILE_L = 64;    // points per block
constexpr int NTHREADS = 256; // 4 waves; wave c handles rows [32c, 32c+32)

// ---------------------------------------------------------------------------
// Kernel 1: C_b = sum_{p,q} (-1)^{p+q} psi[b,p,q]   (16 scalars into d_ws)
// ---------------------------------------------------------------------------
__global__ void cb_kernel(const float* __restrict__ psi, float* __restrict__ cb) {
    __shared__ float red[NTHREADS];
    const int b = blockIdx.x;
    const float* P = psi + (size_t)b * KDIM * KDIM;
    float s = 0.0f;
    for (int e = threadIdx.x; e < KDIM * KDIM; e += NTHREADS) {
        float v = P[e];
        // parity of p+q for flat e = p*128+q:  ((e>>7) ^ e) & 1
        s += (((e >> 7) ^ e) & 1) ? -v : v;
    }
    red[threadIdx.x] = s;
    __syncthreads();
    for (int off = NTHREADS / 2; off > 0; off >>= 1) {
        if (threadIdx.x < off) red[threadIdx.x] += red[threadIdx.x + off];
        __syncthreads();
    }
    if (threadIdx.x == 0) cb[b] = red[0];
}

// ---------------------------------------------------------------------------
// Main kernel: psi_x[b,l] = ( sum_{p,q} psi[p,q] wy[p] wx[q]
//                             - sin(64x) sin(64y) C_b ) / K^2
// w(t) = sin(64 t) * cos(t/2) / sin(t/2),  t_q = pos - 2*pi*q/128
// ---------------------------------------------------------------------------
__launch_bounds__(NTHREADS, 2)
__global__ void main_kernel(const float* __restrict__ x0, const float* __restrict__ y0,
                            const float* __restrict__ psi, const float* __restrict__ cb,
                            float* __restrict__ out) {
    __shared__ float wx[KDIM][TILE_L];   // 32 KB, [q][l]: bank = l%32, conflict-free
    __shared__ float wy[KDIM][TILE_L];   // 32 KB
    __shared__ float xs[TILE_L], ys[TILE_L], sx[TILE_L], sy[TILE_L];
    __shared__ float partial[4][TILE_L];

    const int tid = threadIdx.x;
    const int bid = blockIdx.x;
    const int b  = bid >> 7;              // 128 l-tiles per batch
    const int l0 = (bid & 127) * TILE_L;

    if (tid < TILE_L) {
        float x = x0[(size_t)b * LTOT + l0 + tid];
        xs[tid] = x;
        sx[tid] = sinf(64.0f * x);
    } else if (tid < 2 * TILE_L) {
        int l = tid - TILE_L;
        float y = y0[(size_t)b * LTOT + l0 + l];
        ys[l] = y;
        sy[l] = sinf(64.0f * y);
    }
    __syncthreads();

    // ---- Stage A: build wx[q][l], wy[p][l] (16384 entries over 256 threads)
    const float step = (float)(2.0 * M_PI / 128.0);
    for (int e = tid; e < 2 * KDIM * TILE_L; e += NTHREADS) {
        const int which = e >> 13;                 // 0 -> wx, 1 -> wy
        const int idx = e & (KDIM * TILE_L - 1);
        const int q = idx >> 6;
        const int l = idx & (TILE_L - 1);
        const float pos = which ? ys[l] : xs[l];
        const float t = pos - step * (float)q;
        float w;
        if (t == 0.0f) {
            w = 128.0f;                            // limit of sin(64t)cot(t/2)
        } else {
            float sn, cs;
            sincosf(0.5f * t, &sn, &cs);
            w = sinf(64.0f * t) * cs / sn;         // shared t -> stable ratio
        }
        float* dst = which ? &wy[0][0] : &wx[0][0];
        dst[idx] = w;
    }
    __syncthreads();

    // ---- Stage B: bilinear form. Wave c owns rows [32c, 32c+32), 8 rows per
    // wx-read (register blocking); psi rows are wave-uniform -> scalar loads.
    const int l = tid & (TILE_L - 1);
    const int c = tid >> 6;                        // wave-uniform
    const float* Pb = psi + (size_t)b * KDIM * KDIM;
    float acc = 0.0f;
    for (int rr = 0; rr < 4; ++rr) {
        const int p0 = c * 32 + rr * 8;
        const float* row = Pb + __builtin_amdgcn_readfirstlane(p0 * KDIM);
        float a0 = 0, a1 = 0, a2 = 0, a3 = 0, a4 = 0, a5 = 0, a6 = 0, a7 = 0;
#pragma unroll 8
        for (int q = 0; q < KDIM; ++q) {
            const float wv = wx[q][l];
            a0 = fmaf(row[q      ], wv, a0);
            a1 = fmaf(row[q + 128], wv, a1);
            a2 = fmaf(row[q + 256], wv, a2);
            a3 = fmaf(row[q + 384], wv, a3);
            a4 = fmaf(row[q + 512], wv, a4);
            a5 = fmaf(row[q + 640], wv, a5);
            a6 = fmaf(row[q + 768], wv, a6);
            a7 = fmaf(row[q + 896], wv, a7);
        }
        acc = fmaf(a0, wy[p0 + 0][l], acc);
        acc = fmaf(a1, wy[p0 + 1][l], acc);
        acc = fmaf(a2, wy[p0 + 2][l], acc);
        acc = fmaf(a3, wy[p0 + 3][l], acc);
        acc = fmaf(a4, wy[p0 + 4][l], acc);
        acc = fmaf(a5, wy[p0 + 5][l], acc);
        acc = fmaf(a6, wy[p0 + 6][l], acc);
        acc = fmaf(a7, wy[p0 + 7][l], acc);
    }
    partial[c][l] = acc;
    __syncthreads();

    if (tid < TILE_L) {
        float s = partial[0][tid] + partial[1][tid] + partial[2][tid] + partial[3][tid];
        s = s - sx[tid] * sy[tid] * cb[b];
        out[(size_t)b * LTOT + l0 + tid] = s * (1.0f / 16384.0f);
    }
}

extern "C" void kernel_launch(void* const* d_in, const int* in_sizes, int n_in,
                              void* d_out, int out_size, void* d_ws, size_t ws_size,
                              hipStream_t stream) {
    const float* x0  = (const float*)d_in[0];
    const float* y0  = (const float*)d_in[1];
    const float* psi = (const float*)d_in[2];
    float* out = (float*)d_out;
    float* cb  = (float*)d_ws;   // 16 floats

    cb_kernel<<<16, NTHREADS, 0, stream>>>(psi, cb);
    main_kernel<<<16 * (LTOT / TILE_L), NTHREADS, 0, stream>>>(x0, y0, psi, cb, out);
}

// Round 2
// 92.000 us; speedup vs baseline: 2.9843x; 2.9843x over previous
//
#include <hip/hip_runtime.h>
#include <math.h>

#ifndef M_PI
#define M_PI 3.14159265358979323846
#endif

typedef _Float16 half8v __attribute__((ext_vector_type(8)));
typedef _Float16 half2v __attribute__((ext_vector_type(2)));
typedef float float4v __attribute__((ext_vector_type(4)));

constexpr int KDIM = 128;
constexpr int LTOT = 8192;
constexpr int TILE_L = 64;
constexpr int NT = 256;
constexpr int WSTR = 136;   // LDS row stride in halves (128 + 8 pad)

// ---------------------------------------------------------------------------
// C_b = sum_{p,q} (-1)^{p+q} psi[b,p,q]; 256 blocks, atomicAdd into ws.
// ---------------------------------------------------------------------------
__global__ __launch_bounds__(256) void cb_kernel(const float* __restrict__ psi,
                                                 float* __restrict__ cb) {
    __shared__ float red[4];
    const int b = blockIdx.x >> 4;
    const int slice = blockIdx.x & 15;
    const float* P = psi + (size_t)b * 16384 + slice * 1024;
    const int t = threadIdx.x;
    float4v v = *(const float4v*)(P + t * 4);
    float s = (v.x - v.y) + (v.z - v.w);           // q-parity within the quad
    const int e = slice * 1024 + t * 4;
    if ((e >> 7) & 1) s = -s;                      // p-parity (q0 % 4 == 0)
    for (int off = 1; off < 64; off <<= 1) s += __shfl_xor(s, off, 64);
    if ((t & 63) == 0) red[t >> 6] = s;
    __syncthreads();
    if (t == 0) atomicAdd(&cb[b], (red[0] + red[1]) + (red[2] + red[3]));
}

// ---------------------------------------------------------------------------
// Main: per 64-point tile
//   wx[q][l] = w(x_l - 2*pi*q/128), wy likewise (fp16 in LDS, transposed)
//   tmp = psi * WX via mfma_f32_16x16x32_f16 (M=128,N=64,K=128)
//   out[l] = (sum_p wy[p][l]*tmp[p][l] - sin64x*sin64y*C_b) / K^2
// ---------------------------------------------------------------------------
__global__ __launch_bounds__(NT, 3) void main_kernel(const float* __restrict__ x0,
        const float* __restrict__ y0, const float* __restrict__ psi,
        const float* __restrict__ cbv, float* __restrict__ out) {
    __shared__ _Float16 wxT[TILE_L][WSTR];     // [l][q]
    __shared__ _Float16 wyT[TILE_L][WSTR];     // [l][p]
    __shared__ float cbq[KDIM], sbq[KDIM];     // cos/sin(q*pi/128)
    __shared__ float ndh[KDIM], ndl[KDIM], ndh2[KDIM], ndl2[KDIM]; // two-float nodes
    __shared__ float posA[2][TILE_L], s64A[2][TILE_L], saA[2][TILE_L], caA[2][TILE_L];
    __shared__ float partial[4][TILE_L];

    const int tid = threadIdx.x;
    const int lane = tid & 63;
    const int w = tid >> 6;
    const int bid = blockIdx.x;
    const int b = bid >> 7;
    const int l0 = (bid & 127) * TILE_L;
    const int qd = lane >> 4;          // quad 0..3
    const int ln = lane & 15;

    const float* Pb = psi + (size_t)b * 16384;

    // ---- prefetch A k-step 0 (no LDS dependency; L2-hot) ----
    float4v a_raw[2][2];
#pragma unroll
    for (int mi = 0; mi < 2; ++mi) {
        const float* rp = Pb + (32 * w + 16 * mi + ln) * 128 + 8 * qd;
        a_raw[mi][0] = *(const float4v*)(rp);
        a_raw[mi][1] = *(const float4v*)(rp + 4);
    }

    // ---- tables (threads 0-127) & per-point trig (threads 128-255) ----
    if (tid < KDIM) {
        float bq = (float)tid * (float)(M_PI / 128.0);
        float sn, cs;
        sincosf(bq, &sn, &cs);
        sbq[tid] = sn; cbq[tid] = cs;
        double d = (double)tid * (M_PI / 64.0);
        float h = (float)d, l = (float)(d - (double)h);
        ndh[tid] = h; ndl[tid] = l;
        double d2 = d - 2.0 * M_PI;
        float h2 = (float)d2, l2 = (float)(d2 - (double)h2);
        ndh2[tid] = h2; ndl2[tid] = l2;
    } else {
        const int m = tid - KDIM;
        const int ax = m >> 6;         // 0 = x, 1 = y
        const int l = m & 63;
        const float* src = ax ? y0 : x0;
        float pos = src[(size_t)b * LTOT + l0 + l];
        posA[ax][l] = pos;
        s64A[ax][l] = sinf(64.0f * pos);
        float sa, ca;
        sincosf(0.5f * pos, &sa, &ca);
        saA[ax][l] = sa; caA[ax][l] = ca;
    }
    __syncthreads();

    // ---- build wxT / wyT: w = (-1)^q * sin(64*pos) * cos(t/2) / sin(t/2) ----
    const float step = (float)(M_PI / 64.0);
    for (int it = 0; it < 32; ++it) {
        const int i = tid + NT * it;   // 0..8191 (half2 granules)
        const int mat = i >> 12;       // 0 = wx, 1 = wy (wave-uniform)
        const int r = i & 4095;
        const int l = r >> 6;
        const int qp = r & 63;
        const int q0 = qp << 1;
        const float pos = posA[mat][l];
        const float s64 = s64A[mat][l];
        const float sa = saA[mat][l], ca = caA[mat][l];
        _Float16 wpair[2];
#pragma unroll
        for (int j = 0; j < 2; ++j) {
            const int q = q0 + j;
            const float cq = cbq[q], sq = sbq[q];
            float sn = sa * cq - ca * sq;       // sin(pos/2 - q*pi/128)
            float cs = ca * cq + sa * sq;       // cos(pos/2 - q*pi/128)
            float num = (q & 1) ? -s64 : s64;   // sin(64*t_q) exactly
            float wv;
            if (__builtin_expect(fabsf(sn) >= 1e-3f, 1)) {
                wv = num * cs * __builtin_amdgcn_rcpf(sn);
            } else {
                // near a node: rebuild u = t_q accurately (two-float), Taylor ratio
                float ta = pos - step * (float)q;
                float nh, nl;
                if (ta > -1.0f) { nh = ndh[q];  nl = ndl[q]; }
                else            { nh = ndh2[q]; nl = ndl2[q]; }
                float u = (pos - nh) - nl;
                if (fabsf(u) < 1e-7f) {
                    wv = 128.0f;
                } else {
                    float hh = 0.5f * u;
                    float s2 = hh * (1.0f - 0.16666667f * hh * hh);
                    float c2 = 1.0f - 0.5f * hh * hh;
                    wv = num * c2 * __builtin_amdgcn_rcpf(s2);
                }
            }
            wpair[j] = (_Float16)wv;
        }
        _Float16* dst = mat ? &wyT[0][0] : &wxT[0][0];
        *(half2v*)&dst[l * WSTR + q0] = *(half2v*)wpair;
    }
    __syncthreads();

    // ---- GEMM: wave w owns rows [32w,32w+32) (m-tiles 2w,2w+1), all 4 n-tiles
    float4v acc[2][4];
#pragma unroll
    for (int mi = 0; mi < 2; ++mi)
#pragma unroll
        for (int ni = 0; ni < 4; ++ni) acc[mi][ni] = (float4v){0.f, 0.f, 0.f, 0.f};

#pragma unroll
    for (int k = 0; k < 4; ++k) {
        half8v af[2];
#pragma unroll
        for (int mi = 0; mi < 2; ++mi) {
#pragma unroll
            for (int j = 0; j < 4; ++j) {
                af[mi][j]     = (_Float16)a_raw[mi][0][j];
                af[mi][4 + j] = (_Float16)a_raw[mi][1][j];
            }
        }
        if (k < 3) {   // prefetch next k-step
#pragma unroll
            for (int mi = 0; mi < 2; ++mi) {
                const float* rp = Pb + (32 * w + 16 * mi + ln) * 128 + (k + 1) * 32 + 8 * qd;
                a_raw[mi][0] = *(const float4v*)(rp);
                a_raw[mi][1] = *(const float4v*)(rp + 4);
            }
        }
#pragma unroll
        for (int ni = 0; ni < 4; ++ni) {
            half8v bf = *(const half8v*)&wxT[16 * ni + ln][k * 32 + 8 * qd];
#pragma unroll
            for (int mi = 0; mi < 2; ++mi)
                acc[mi][ni] = __builtin_amdgcn_mfma_f32_16x16x32_f16(af[mi], bf, acc[mi][ni], 0, 0, 0);
        }
    }

    // ---- reduce over p: C/D layout p = 32w+16mi+4qd+reg, l = 16ni+ln ----
    float part[4];
#pragma unroll
    for (int ni = 0; ni < 4; ++ni) {
        float s = 0.f;
#pragma unroll
        for (int mi = 0; mi < 2; ++mi) {
            const _Float16* wp = &wyT[16 * ni + ln][32 * w + 16 * mi + 4 * qd];
            half2v w01 = *(const half2v*)(wp);
            half2v w23 = *(const half2v*)(wp + 2);
            s += acc[mi][ni][0] * (float)w01[0] + acc[mi][ni][1] * (float)w01[1]
               + acc[mi][ni][2] * (float)w23[0] + acc[mi][ni][3] * (float)w23[1];
        }
        s += __shfl_xor(s, 16, 64);
        s += __shfl_xor(s, 32, 64);
        part[ni] = s;
    }
    if (qd == 0) {
#pragma unroll
        for (int ni = 0; ni < 4; ++ni) partial[w][16 * ni + ln] = part[ni];
    }
    __syncthreads();

    if (tid < TILE_L) {
        float s = (partial[0][tid] + partial[1][tid]) + (partial[2][tid] + partial[3][tid]);
        s -= s64A[0][tid] * s64A[1][tid] * cbv[b];
        out[(size_t)b * LTOT + l0 + tid] = s * (1.0f / 16384.0f);
    }
}

extern "C" void kernel_launch(void* const* d_in, const int* in_sizes, int n_in,
                              void* d_out, int out_size, void* d_ws, size_t ws_size,
                              hipStream_t stream) {
    const float* x0  = (const float*)d_in[0];
    const float* y0  = (const float*)d_in[1];
    const float* psi = (const float*)d_in[2];
    float* out = (float*)d_out;
    float* cb  = (float*)d_ws;     // 16 floats

    hipMemsetAsync(d_ws, 0, 16 * sizeof(float), stream);
    cb_kernel<<<256, 256, 0, stream>>>(psi, cb);
    main_kernel<<<16 * (LTOT / TILE_L), NT, 0, stream>>>(x0, y0, psi, cb, out);
}

// Round 6
// 88.522 us; speedup vs baseline: 3.1015x; 1.0393x over previous
//
#include <hip/hip_runtime.h>
#include <math.h>

#ifndef M_PI
#define M_PI 3.14159265358979323846
#endif

typedef _Float16 half8v __attribute__((ext_vector_type(8)));
typedef _Float16 half2v __attribute__((ext_vector_type(2)));
typedef float float4v __attribute__((ext_vector_type(4)));

constexpr int KDIM = 128;
constexpr int LTOT = 8192;
constexpr int TILE_L = 64;
constexpr int NT = 256;
constexpr int WSTR = 136;   // LDS row stride in halves (128 + 8 pad)

// ---------------------------------------------------------------------------
// C_b = sum_{p,q} (-1)^{p+q} psi[b,p,q]; 256 blocks, atomicAdd into ws.
// (verbatim from the 92us passing run)
// ---------------------------------------------------------------------------
__global__ __launch_bounds__(256) void cb_kernel(const float* __restrict__ psi,
                                                 float* __restrict__ cb) {
    __shared__ float red[4];
    const int b = blockIdx.x >> 4;
    const int slice = blockIdx.x & 15;
    const float* P = psi + (size_t)b * 16384 + slice * 1024;
    const int t = threadIdx.x;
    float4v v = *(const float4v*)(P + t * 4);
    float s = (v.x - v.y) + (v.z - v.w);           // q-parity within the quad
    const int e = slice * 1024 + t * 4;
    if ((e >> 7) & 1) s = -s;                      // p-parity
    for (int off = 1; off < 64; off <<= 1) s += __shfl_xor(s, off, 64);
    if ((t & 63) == 0) red[t >> 6] = s;
    __syncthreads();
    if (t == 0) atomicAdd(&cb[b], (red[0] + red[1]) + (red[2] + red[3]));
}

// ---------------------------------------------------------------------------
// Main: 92us passing structure; ONLY the wx/wy build loop is replaced by the
// rotation-recurrence build (validated launch-once in round 3). A k0-prefetch
// moved to after the build so no a_raw registers are live across it.
// ---------------------------------------------------------------------------
__global__ __launch_bounds__(NT, 3) void main_kernel(const float* __restrict__ x0,
        const float* __restrict__ y0, const float* __restrict__ psi,
        const float* __restrict__ cbv, float* __restrict__ out) {
    __shared__ _Float16 wxT[TILE_L][WSTR];         // [l][q]
    __shared__ _Float16 wyT[TILE_L][WSTR];         // [l][p]
    __shared__ float ndh[KDIM], ndl[KDIM], ndh2[KDIM], ndl2[KDIM];
    __shared__ float s64A[2][TILE_L];
    __shared__ float partial[4][TILE_L];

    const int tid = threadIdx.x;
    const int lane = tid & 63;
    const int w = tid >> 6;
    const int bid = blockIdx.x;
    const int b = bid >> 7;
    const int l0 = (bid & 127) * TILE_L;
    const int qd = lane >> 4;          // quad 0..3
    const int ln = lane & 15;

    const float* Pb = psi + (size_t)b * 16384;

    // ---- node tables for the rare slow path (round-3 text) ----
    if (tid < KDIM) {
        double d = (double)tid * (M_PI / 64.0);
        float h = (float)d;
        ndh[tid] = h; ndl[tid] = (float)(d - (double)h);
        double d2 = d - 2.0 * M_PI;
        float h2 = (float)d2;
        ndh2[tid] = h2; ndl2[tid] = (float)(d2 - (double)h2);
    }

    // ---- per-thread build setup: one column (mat,l), q-range [64*hf, +64) ----
    const int col = tid & 127;
    const int mat = col >> 6;                      // 0 = wx, 1 = wy
    const int l = col & 63;
    const int hf = tid >> 7;
    const float* src = mat ? y0 : x0;
    const float pos = src[(size_t)b * LTOT + l0 + l];
    const float s64 = sinf(64.0f * pos);
    float sa, ca;
    sincosf(0.5f * pos, &sa, &ca);
    float cs_s, cs_c;                              // seed: sin/cos(pos/2 - 64*hf*beta)
    if (hf == 0) { cs_s = sa; cs_c = ca; s64A[mat][l] = s64; }
    else         { cs_s = -ca; cs_c = sa; }        // exact rotate by -pi/2
    __syncthreads();

    // ---- build: w(t_q) = (-1)^q sin(64 pos) * cos(th)/sin(th), th = pos/2 - q*beta
    _Float16* dst = mat ? &wyT[l][0] : &wxT[l][0];
    const float CB  = 0.9996988186962042f,  SB  = 0.024541228522912288f;  // beta = pi/128
    const float C16 = 0.9238795325112867f,  S16 = 0.3826834323650898f;    // 16*beta
    const float step = (float)(M_PI / 64.0);
#pragma unroll
    for (int kk = 0; kk < 4; ++kk) {
        float ws_ = cs_s, wc_ = cs_c;
        const int q0 = 64 * hf + 16 * kk;
#pragma unroll
        for (int h8 = 0; h8 < 2; ++h8) {
            _Float16 buf[8];
#pragma unroll
            for (int j = 0; j < 8; ++j) {
                const int q = q0 + 8 * h8 + j;
                const float num = (j & 1) ? -s64 : s64;   // sin(64 t_q) exactly
                float wv;
                if (__builtin_expect(fabsf(ws_) >= 2e-3f, 1)) {
                    wv = num * wc_ * __builtin_amdgcn_rcpf(ws_);
                } else {
                    // near grid node: rebuild u = t_q in two-float, Taylor ratio
                    float ta = pos - step * (float)q;
                    float nh, nl;
                    if (ta > -1.0f) { nh = ndh[q];  nl = ndl[q]; }
                    else            { nh = ndh2[q]; nl = ndl2[q]; }
                    float u = (pos - nh) - nl;
                    if (fabsf(u) < 1e-7f) {
                        wv = 128.0f;
                    } else {
                        float hh = 0.5f * u;
                        float s2 = hh * (1.0f - 0.16666667f * hh * hh);
                        float c2 = 1.0f - 0.5f * hh * hh;
                        wv = num * c2 * __builtin_amdgcn_rcpf(s2);
                    }
                }
                buf[j] = (_Float16)wv;
                float ns = ws_ * CB - wc_ * SB;    // rotate by -beta
                wc_ = wc_ * CB + ws_ * SB;
                ws_ = ns;
            }
            *(half8v*)&dst[q0 + 8 * h8] = *(half8v*)buf;
        }
        float ns = cs_s * C16 - cs_c * S16;        // reseed: rotate by -16*beta
        cs_c = cs_c * C16 + cs_s * S16;
        cs_s = ns;
    }
    __syncthreads();

    // ---- A k0 load (fp32, L2-hot), AFTER the build: no liveness across it ----
    float4v a_raw[2][2];
#pragma unroll
    for (int mi = 0; mi < 2; ++mi) {
        const float* rp = Pb + (32 * w + 16 * mi + ln) * 128 + 8 * qd;
        a_raw[mi][0] = *(const float4v*)(rp);
        a_raw[mi][1] = *(const float4v*)(rp + 4);
    }

    // ---- GEMM: verbatim 92us loop shape (convert, reload in place, MFMA) ----
    float4v acc[2][4];
#pragma unroll
    for (int mi = 0; mi < 2; ++mi)
#pragma unroll
        for (int ni = 0; ni < 4; ++ni) acc[mi][ni] = (float4v){0.f, 0.f, 0.f, 0.f};

#pragma unroll
    for (int k = 0; k < 4; ++k) {
        half8v af[2];
#pragma unroll
        for (int mi = 0; mi < 2; ++mi) {
#pragma unroll
            for (int j = 0; j < 4; ++j) {
                af[mi][j]     = (_Float16)a_raw[mi][0][j];
                af[mi][4 + j] = (_Float16)a_raw[mi][1][j];
            }
        }
        if (k < 3) {   // prefetch next k-step (af already captured the values)
#pragma unroll
            for (int mi = 0; mi < 2; ++mi) {
                const float* rp = Pb + (32 * w + 16 * mi + ln) * 128 + (k + 1) * 32 + 8 * qd;
                a_raw[mi][0] = *(const float4v*)(rp);
                a_raw[mi][1] = *(const float4v*)(rp + 4);
            }
        }
#pragma unroll
        for (int ni = 0; ni < 4; ++ni) {
            half8v bf = *(const half8v*)&wxT[16 * ni + ln][k * 32 + 8 * qd];
#pragma unroll
            for (int mi = 0; mi < 2; ++mi)
                acc[mi][ni] = __builtin_amdgcn_mfma_f32_16x16x32_f16(af[mi], bf, acc[mi][ni], 0, 0, 0);
        }
    }

    // ---- reduce over p: C/D layout p = 32w+16mi+4qd+reg, l = 16ni+ln ----
    float part[4];
#pragma unroll
    for (int ni = 0; ni < 4; ++ni) {
        float s = 0.f;
#pragma unroll
        for (int mi = 0; mi < 2; ++mi) {
            const _Float16* wp = &wyT[16 * ni + ln][32 * w + 16 * mi + 4 * qd];
            half2v w01 = *(const half2v*)(wp);
            half2v w23 = *(const half2v*)(wp + 2);
            s += acc[mi][ni][0] * (float)w01[0] + acc[mi][ni][1] * (float)w01[1]
               + acc[mi][ni][2] * (float)w23[0] + acc[mi][ni][3] * (float)w23[1];
        }
        s += __shfl_xor(s, 16, 64);
        s += __shfl_xor(s, 32, 64);
        part[ni] = s;
    }
    if (qd == 0) {
#pragma unroll
        for (int ni = 0; ni < 4; ++ni) partial[w][16 * ni + ln] = part[ni];
    }
    __syncthreads();

    if (tid < TILE_L) {
        float s = (partial[0][tid] + partial[1][tid]) + (partial[2][tid] + partial[3][tid]);
        s -= s64A[0][tid] * s64A[1][tid] * cbv[b];
        out[(size_t)b * LTOT + l0 + tid] = s * (1.0f / 16384.0f);
    }
}

extern "C" void kernel_launch(void* const* d_in, const int* in_sizes, int n_in,
                              void* d_out, int out_size, void* d_ws, size_t ws_size,
                              hipStream_t stream) {
    const float* x0  = (const float*)d_in[0];
    const float* y0  = (const float*)d_in[1];
    const float* psi = (const float*)d_in[2];
    float* out = (float*)d_out;
    float* cb  = (float*)d_ws;     // 16 floats

    hipMemsetAsync(d_ws, 0, 16 * sizeof(float), stream);
    cb_kernel<<<256, 256, 0, stream>>>(psi, cb);
    main_kernel<<<16 * (LTOT / TILE_L), NT, 0, stream>>>(x0, y0, psi, cb, out);
}

// Round 7
// 84.749 us; speedup vs baseline: 3.2396x; 1.0445x over previous
//
#include <hip/hip_runtime.h>
#include <math.h>

#ifndef M_PI
#define M_PI 3.14159265358979323846
#endif

typedef _Float16 half8v __attribute__((ext_vector_type(8)));
typedef _Float16 half2v __attribute__((ext_vector_type(2)));
typedef float float4v __attribute__((ext_vector_type(4)));

constexpr int KDIM = 128;
constexpr int LTOT = 8192;
constexpr int TILE_L = 64;
constexpr int NT = 256;
constexpr int WSTR = 136;   // LDS row stride in halves (128 + 8 pad)

// ---------------------------------------------------------------------------
// C_b = sum_{p,q} (-1)^{p+q} psi[b,p,q]; one block per batch, direct store
// (no atomics, no memset dispatch). Same reduce arithmetic as the validated
// 256-block version, just sliced per-batch.
// ---------------------------------------------------------------------------
__global__ __launch_bounds__(256) void cb_kernel(const float* __restrict__ psi,
                                                 float* __restrict__ cb) {
    __shared__ float red[4];
    const int b = blockIdx.x;
    const float* P = psi + (size_t)b * 16384;
    const int t = threadIdx.x;
    float s = 0.0f;
#pragma unroll 4
    for (int it = 0; it < 16; ++it) {
        float4v v = *(const float4v*)(P + it * 1024 + t * 4);
        float sv = (v.x - v.y) + (v.z - v.w);      // q-parity within the quad
        const int e = it * 1024 + t * 4;
        if ((e >> 7) & 1) sv = -sv;                // p-parity
        s += sv;
    }
    for (int off = 1; off < 64; off <<= 1) s += __shfl_xor(s, off, 64);
    if ((t & 63) == 0) red[t >> 6] = s;
    __syncthreads();
    if (t == 0) cb[b] = (red[0] + red[1]) + (red[2] + red[3]);
}

// ---------------------------------------------------------------------------
// Main: byte-identical to the round-6 passing kernel except
// __launch_bounds__ 3 -> 4 (VGPR 88 < 128 cap, LDS 38.4 KB -> 4 blocks/CU).
// ---------------------------------------------------------------------------
__global__ __launch_bounds__(NT, 4) void main_kernel(const float* __restrict__ x0,
        const float* __restrict__ y0, const float* __restrict__ psi,
        const float* __restrict__ cbv, float* __restrict__ out) {
    __shared__ _Float16 wxT[TILE_L][WSTR];         // [l][q]
    __shared__ _Float16 wyT[TILE_L][WSTR];         // [l][p]
    __shared__ float ndh[KDIM], ndl[KDIM], ndh2[KDIM], ndl2[KDIM];
    __shared__ float s64A[2][TILE_L];
    __shared__ float partial[4][TILE_L];

    const int tid = threadIdx.x;
    const int lane = tid & 63;
    const int w = tid >> 6;
    const int bid = blockIdx.x;
    const int b = bid >> 7;
    const int l0 = (bid & 127) * TILE_L;
    const int qd = lane >> 4;          // quad 0..3
    const int ln = lane & 15;

    const float* Pb = psi + (size_t)b * 16384;

    // ---- node tables for the rare slow path ----
    if (tid < KDIM) {
        double d = (double)tid * (M_PI / 64.0);
        float h = (float)d;
        ndh[tid] = h; ndl[tid] = (float)(d - (double)h);
        double d2 = d - 2.0 * M_PI;
        float h2 = (float)d2;
        ndh2[tid] = h2; ndl2[tid] = (float)(d2 - (double)h2);
    }

    // ---- per-thread build setup: one column (mat,l), q-range [64*hf, +64) ----
    const int col = tid & 127;
    const int mat = col >> 6;                      // 0 = wx, 1 = wy
    const int l = col & 63;
    const int hf = tid >> 7;
    const float* src = mat ? y0 : x0;
    const float pos = src[(size_t)b * LTOT + l0 + l];
    const float s64 = sinf(64.0f * pos);
    float sa, ca;
    sincosf(0.5f * pos, &sa, &ca);
    float cs_s, cs_c;                              // seed: sin/cos(pos/2 - 64*hf*beta)
    if (hf == 0) { cs_s = sa; cs_c = ca; s64A[mat][l] = s64; }
    else         { cs_s = -ca; cs_c = sa; }        // exact rotate by -pi/2
    __syncthreads();

    // ---- build: w(t_q) = (-1)^q sin(64 pos) * cos(th)/sin(th), th = pos/2 - q*beta
    _Float16* dst = mat ? &wyT[l][0] : &wxT[l][0];
    const float CB  = 0.9996988186962042f,  SB  = 0.024541228522912288f;  // beta = pi/128
    const float C16 = 0.9238795325112867f,  S16 = 0.3826834323650898f;    // 16*beta
    const float step = (float)(M_PI / 64.0);
#pragma unroll
    for (int kk = 0; kk < 4; ++kk) {
        float ws_ = cs_s, wc_ = cs_c;
        const int q0 = 64 * hf + 16 * kk;
#pragma unroll
        for (int h8 = 0; h8 < 2; ++h8) {
            _Float16 buf[8];
#pragma unroll
            for (int j = 0; j < 8; ++j) {
                const int q = q0 + 8 * h8 + j;
                const float num = (j & 1) ? -s64 : s64;   // sin(64 t_q) exactly
                float wv;
                if (__builtin_expect(fabsf(ws_) >= 2e-3f, 1)) {
                    wv = num * wc_ * __builtin_amdgcn_rcpf(ws_);
                } else {
                    // near grid node: rebuild u = t_q in two-float, Taylor ratio
                    float ta = pos - step * (float)q;
                    float nh, nl;
                    if (ta > -1.0f) { nh = ndh[q];  nl = ndl[q]; }
                    else            { nh = ndh2[q]; nl = ndl2[q]; }
                    float u = (pos - nh) - nl;
                    if (fabsf(u) < 1e-7f) {
                        wv = 128.0f;
                    } else {
                        float hh = 0.5f * u;
                        float s2 = hh * (1.0f - 0.16666667f * hh * hh);
                        float c2 = 1.0f - 0.5f * hh * hh;
                        wv = num * c2 * __builtin_amdgcn_rcpf(s2);
                    }
                }
                buf[j] = (_Float16)wv;
                float ns = ws_ * CB - wc_ * SB;    // rotate by -beta
                wc_ = wc_ * CB + ws_ * SB;
                ws_ = ns;
            }
            *(half8v*)&dst[q0 + 8 * h8] = *(half8v*)buf;
        }
        float ns = cs_s * C16 - cs_c * S16;        // reseed: rotate by -16*beta
        cs_c = cs_c * C16 + cs_s * S16;
        cs_s = ns;
    }
    __syncthreads();

    // ---- A k0 load (fp32, L2-hot), AFTER the build: no liveness across it ----
    float4v a_raw[2][2];
#pragma unroll
    for (int mi = 0; mi < 2; ++mi) {
        const float* rp = Pb + (32 * w + 16 * mi + ln) * 128 + 8 * qd;
        a_raw[mi][0] = *(const float4v*)(rp);
        a_raw[mi][1] = *(const float4v*)(rp + 4);
    }

    // ---- GEMM: validated loop shape (convert, reload in place, MFMA) ----
    float4v acc[2][4];
#pragma unroll
    for (int mi = 0; mi < 2; ++mi)
#pragma unroll
        for (int ni = 0; ni < 4; ++ni) acc[mi][ni] = (float4v){0.f, 0.f, 0.f, 0.f};

#pragma unroll
    for (int k = 0; k < 4; ++k) {
        half8v af[2];
#pragma unroll
        for (int mi = 0; mi < 2; ++mi) {
#pragma unroll
            for (int j = 0; j < 4; ++j) {
                af[mi][j]     = (_Float16)a_raw[mi][0][j];
                af[mi][4 + j] = (_Float16)a_raw[mi][1][j];
            }
        }
        if (k < 3) {   // prefetch next k-step (af already captured the values)
#pragma unroll
            for (int mi = 0; mi < 2; ++mi) {
                const float* rp = Pb + (32 * w + 16 * mi + ln) * 128 + (k + 1) * 32 + 8 * qd;
                a_raw[mi][0] = *(const float4v*)(rp);
                a_raw[mi][1] = *(const float4v*)(rp + 4);
            }
        }
#pragma unroll
        for (int ni = 0; ni < 4; ++ni) {
            half8v bf = *(const half8v*)&wxT[16 * ni + ln][k * 32 + 8 * qd];
#pragma unroll
            for (int mi = 0; mi < 2; ++mi)
                acc[mi][ni] = __builtin_amdgcn_mfma_f32_16x16x32_f16(af[mi], bf, acc[mi][ni], 0, 0, 0);
        }
    }

    // ---- reduce over p: C/D layout p = 32w+16mi+4qd+reg, l = 16ni+ln ----
    float part[4];
#pragma unroll
    for (int ni = 0; ni < 4; ++ni) {
        float s = 0.f;
#pragma unroll
        for (int mi = 0; mi < 2; ++mi) {
            const _Float16* wp = &wyT[16 * ni + ln][32 * w + 16 * mi + 4 * qd];
            half2v w01 = *(const half2v*)(wp);
            half2v w23 = *(const half2v*)(wp + 2);
            s += acc[mi][ni][0] * (float)w01[0] + acc[mi][ni][1] * (float)w01[1]
               + acc[mi][ni][2] * (float)w23[0] + acc[mi][ni][3] * (float)w23[1];
        }
        s += __shfl_xor(s, 16, 64);
        s += __shfl_xor(s, 32, 64);
        part[ni] = s;
    }
    if (qd == 0) {
#pragma unroll
        for (int ni = 0; ni < 4; ++ni) partial[w][16 * ni + ln] = part[ni];
    }
    __syncthreads();

    if (tid < TILE_L) {
        float s = (partial[0][tid] + partial[1][tid]) + (partial[2][tid] + partial[3][tid]);
        s -= s64A[0][tid] * s64A[1][tid] * cbv[b];
        out[(size_t)b * LTOT + l0 + tid] = s * (1.0f / 16384.0f);
    }
}

extern "C" void kernel_launch(void* const* d_in, const int* in_sizes, int n_in,
                              void* d_out, int out_size, void* d_ws, size_t ws_size,
                              hipStream_t stream) {
    const float* x0  = (const float*)d_in[0];
    const float* y0  = (const float*)d_in[1];
    const float* psi = (const float*)d_in[2];
    float* out = (float*)d_out;
    float* cb  = (float*)d_ws;     // 16 floats, fully overwritten by cb_kernel

    cb_kernel<<<16, 256, 0, stream>>>(psi, cb);
    main_kernel<<<16 * (LTOT / TILE_L), NT, 0, stream>>>(x0, y0, psi, cb, out);
}

// Round 8
// 82.583 us; speedup vs baseline: 3.3246x; 1.0262x over previous
//
#include <hip/hip_runtime.h>
#include <math.h>

#ifndef M_PI
#define M_PI 3.14159265358979323846
#endif

typedef _Float16 half8v __attribute__((ext_vector_type(8)));
typedef _Float16 half2v __attribute__((ext_vector_type(2)));
typedef float float4v __attribute__((ext_vector_type(4)));

constexpr int KDIM = 128;
constexpr int LTOT = 8192;
constexpr int TILE_L = 64;
constexpr int NT = 256;
constexpr int WSTR = 136;   // LDS row stride in halves (128 + 8 pad)

// ---------------------------------------------------------------------------
// Single kernel (no workspace, fully deterministic). Per 64-point tile:
//   wx/wy  : Dirichlet weights via rotation recurrence (validated R3/R6/R7)
//   tmp    = psi * WX via mfma_f32_16x16x32_f16 (R7 loop shape)
//   C_b    = sum (-1)^{p+q} psi, accumulated from the GEMM's own A loads
//            (block reads the full 64 KB psi batch exactly once: p=32w+16mi+ln,
//             q=32k+8qd+j; sign = (-1)^{(ln&1)+(j&1)})
//   out[l] = (sum_p wy[p][l]*tmp[p][l] - sin64x*sin64y*C_b) / K^2
// RULE (R4-R7 isolation): never hold A-fragment registers live across the
// unrolled build loop — a_raw is loaded strictly after it.
// ---------------------------------------------------------------------------
__global__ __launch_bounds__(NT, 4) void main_kernel(const float* __restrict__ x0,
        const float* __restrict__ y0, const float* __restrict__ psi,
        float* __restrict__ out) {
    __shared__ _Float16 wxT[TILE_L][WSTR];         // [l][q]
    __shared__ _Float16 wyT[TILE_L][WSTR];         // [l][p]
    __shared__ float ndh[KDIM], ndl[KDIM], ndh2[KDIM], ndl2[KDIM];
    __shared__ float s64A[2][TILE_L];
    __shared__ float partial[4][TILE_L];
    __shared__ float cbred[4];

    const int tid = threadIdx.x;
    const int lane = tid & 63;
    const int w = tid >> 6;
    const int bid = blockIdx.x;
    const int b = bid >> 7;
    const int l0 = (bid & 127) * TILE_L;
    const int qd = lane >> 4;          // quad 0..3
    const int ln = lane & 15;

    const float* Pb = psi + (size_t)b * 16384;

    // ---- node tables for the rare slow path ----
    if (tid < KDIM) {
        double d = (double)tid * (M_PI / 64.0);
        float h = (float)d;
        ndh[tid] = h; ndl[tid] = (float)(d - (double)h);
        double d2 = d - 2.0 * M_PI;
        float h2 = (float)d2;
        ndh2[tid] = h2; ndl2[tid] = (float)(d2 - (double)h2);
    }

    // ---- per-thread build setup: one column (mat,l), q-range [64*hf, +64) ----
    const int col = tid & 127;
    const int mat = col >> 6;                      // 0 = wx, 1 = wy
    const int l = col & 63;
    const int hf = tid >> 7;
    const float* src = mat ? y0 : x0;
    const float pos = src[(size_t)b * LTOT + l0 + l];
    const float s64 = sinf(64.0f * pos);
    float sa, ca;
    sincosf(0.5f * pos, &sa, &ca);
    float cs_s, cs_c;                              // seed: sin/cos(pos/2 - 64*hf*beta)
    if (hf == 0) { cs_s = sa; cs_c = ca; s64A[mat][l] = s64; }
    else         { cs_s = -ca; cs_c = sa; }        // exact rotate by -pi/2
    __syncthreads();

    // ---- build: w(t_q) = (-1)^q sin(64 pos) * cos(th)/sin(th), th = pos/2 - q*beta
    _Float16* dst = mat ? &wyT[l][0] : &wxT[l][0];
    const float CB  = 0.9996988186962042f,  SB  = 0.024541228522912288f;  // beta = pi/128
    const float C16 = 0.9238795325112867f,  S16 = 0.3826834323650898f;    // 16*beta
    const float step = (float)(M_PI / 64.0);
#pragma unroll
    for (int kk = 0; kk < 4; ++kk) {
        float ws_ = cs_s, wc_ = cs_c;
        const int q0 = 64 * hf + 16 * kk;
#pragma unroll
        for (int h8 = 0; h8 < 2; ++h8) {
            _Float16 buf[8];
#pragma unroll
            for (int j = 0; j < 8; ++j) {
                const int q = q0 + 8 * h8 + j;
                const float num = (j & 1) ? -s64 : s64;   // sin(64 t_q) exactly
                float wv;
                if (__builtin_expect(fabsf(ws_) >= 2e-3f, 1)) {
                    wv = num * wc_ * __builtin_amdgcn_rcpf(ws_);
                } else {
                    // near grid node: rebuild u = t_q in two-float, Taylor ratio
                    float ta = pos - step * (float)q;
                    float nh, nl;
                    if (ta > -1.0f) { nh = ndh[q];  nl = ndl[q]; }
                    else            { nh = ndh2[q]; nl = ndl2[q]; }
                    float u = (pos - nh) - nl;
                    if (fabsf(u) < 1e-7f) {
                        wv = 128.0f;
                    } else {
                        float hh = 0.5f * u;
                        float s2 = hh * (1.0f - 0.16666667f * hh * hh);
                        float c2 = 1.0f - 0.5f * hh * hh;
                        wv = num * c2 * __builtin_amdgcn_rcpf(s2);
                    }
                }
                buf[j] = (_Float16)wv;
                float ns = ws_ * CB - wc_ * SB;    // rotate by -beta
                wc_ = wc_ * CB + ws_ * SB;
                ws_ = ns;
            }
            *(half8v*)&dst[q0 + 8 * h8] = *(half8v*)buf;
        }
        float ns = cs_s * C16 - cs_c * S16;        // reseed: rotate by -16*beta
        cs_c = cs_c * C16 + cs_s * S16;
        cs_s = ns;
    }
    __syncthreads();

    // ---- A k0 load (fp32, L2/HBM), strictly AFTER the build ----
    float4v a_raw[2][2];
#pragma unroll
    for (int mi = 0; mi < 2; ++mi) {
        const float* rp = Pb + (32 * w + 16 * mi + ln) * 128 + 8 * qd;
        a_raw[mi][0] = *(const float4v*)(rp);
        a_raw[mi][1] = *(const float4v*)(rp + 4);
    }

    // ---- GEMM + in-flight C_b from the same A values ----
    float4v acc[2][4];
#pragma unroll
    for (int mi = 0; mi < 2; ++mi)
#pragma unroll
        for (int ni = 0; ni < 4; ++ni) acc[mi][ni] = (float4v){0.f, 0.f, 0.f, 0.f};

    float cbs = 0.0f;
#pragma unroll
    for (int k = 0; k < 4; ++k) {
        half8v af[2];
#pragma unroll
        for (int mi = 0; mi < 2; ++mi) {
#pragma unroll
            for (int j = 0; j < 4; ++j) {
                af[mi][j]     = (_Float16)a_raw[mi][0][j];
                af[mi][4 + j] = (_Float16)a_raw[mi][1][j];
            }
            cbs += (a_raw[mi][0].x - a_raw[mi][0].y) + (a_raw[mi][0].z - a_raw[mi][0].w)
                 + (a_raw[mi][1].x - a_raw[mi][1].y) + (a_raw[mi][1].z - a_raw[mi][1].w);
        }
        if (k < 3) {   // prefetch next k-step (af/cbs already captured the values)
#pragma unroll
            for (int mi = 0; mi < 2; ++mi) {
                const float* rp = Pb + (32 * w + 16 * mi + ln) * 128 + (k + 1) * 32 + 8 * qd;
                a_raw[mi][0] = *(const float4v*)(rp);
                a_raw[mi][1] = *(const float4v*)(rp + 4);
            }
        }
#pragma unroll
        for (int ni = 0; ni < 4; ++ni) {
            half8v bf = *(const half8v*)&wxT[16 * ni + ln][k * 32 + 8 * qd];
#pragma unroll
            for (int mi = 0; mi < 2; ++mi)
                acc[mi][ni] = __builtin_amdgcn_mfma_f32_16x16x32_f16(af[mi], bf, acc[mi][ni], 0, 0, 0);
        }
    }

    // row-parity sign, deterministic wave reduction, one partial per wave
    if (ln & 1) cbs = -cbs;
#pragma unroll
    for (int off = 1; off < 64; off <<= 1) cbs += __shfl_xor(cbs, off, 64);
    if (lane == 0) cbred[w] = cbs;

    // ---- reduce over p: C/D layout p = 32w+16mi+4qd+reg, l = 16ni+ln ----
    float part[4];
#pragma unroll
    for (int ni = 0; ni < 4; ++ni) {
        float s = 0.f;
#pragma unroll
        for (int mi = 0; mi < 2; ++mi) {
            const _Float16* wp = &wyT[16 * ni + ln][32 * w + 16 * mi + 4 * qd];
            half2v w01 = *(const half2v*)(wp);
            half2v w23 = *(const half2v*)(wp + 2);
            s += acc[mi][ni][0] * (float)w01[0] + acc[mi][ni][1] * (float)w01[1]
               + acc[mi][ni][2] * (float)w23[0] + acc[mi][ni][3] * (float)w23[1];
        }
        s += __shfl_xor(s, 16, 64);
        s += __shfl_xor(s, 32, 64);
        part[ni] = s;
    }
    if (qd == 0) {
#pragma unroll
        for (int ni = 0; ni < 4; ++ni) partial[w][16 * ni + ln] = part[ni];
    }
    __syncthreads();

    if (tid < TILE_L) {
        float cb = (cbred[0] + cbred[1]) + (cbred[2] + cbred[3]);
        float s = (partial[0][tid] + partial[1][tid]) + (partial[2][tid] + partial[3][tid]);
        s -= s64A[0][tid] * s64A[1][tid] * cb;
        out[(size_t)b * LTOT + l0 + tid] = s * (1.0f / 16384.0f);
    }
}

extern "C" void kernel_launch(void* const* d_in, const int* in_sizes, int n_in,
                              void* d_out, int out_size, void* d_ws, size_t ws_size,
                              hipStream_t stream) {
    const float* x0  = (const float*)d_in[0];
    const float* y0  = (const float*)d_in[1];
    const float* psi = (const float*)d_in[2];
    float* out = (float*)d_out;
    (void)d_ws; (void)ws_size;   // unused: single self-contained kernel

    main_kernel<<<16 * (LTOT / TILE_L), NT, 0, stream>>>(x0, y0, psi, out);
}